// Round 5
// baseline (342.459 us; speedup 1.0000x reference)
//
#include <hip/hip_runtime.h>
#include <hip/hip_bf16.h>

// Head: x(8,2048,1024) fp32 @ {Wq,Wk,Wv}(1024,128) fp32
//   -> causal softmax((QK^T)/32) @ V -> out FP32.
// Interface model (pinned rounds 0-4): ALL inputs fp32, OUTPUT fp32.
//   - r1 (inputs as bf16) -> NaN: x is fp32.
//   - r4 on-device dtype sniff changed nothing: all inputs fp32.
//   - r0 "bf16-exact max|ref|" was a %.6e printf artifact; output is fp32
//     (r2/r3 bf16 stores half-filled the fp32 buffer -> stable absmax 4.2578).
// MFMA pipeline differentially VALIDATED: r2 (MFMA) and r3 (scalar audited)
// produced identical absmax -> fragment layouts / softmax / transpose correct.

typedef __attribute__((ext_vector_type(8))) short bf16x8;   // 8 bf16 = 4 VGPRs (MFMA A/B frag)
typedef __attribute__((ext_vector_type(4))) float f32x4;    // MFMA C/D frag

#define NB   8
#define TT   2048
#define CDIM 1024
#define HD   128
#define NTOK (NB * TT)   // 16384
#define NW   384         // Q|K|V output columns concatenated

using bf16 = __hip_bfloat16;

__device__ __forceinline__ short f2bs(float f) {
    bf16 h = __float2bfloat16(f);
    return *reinterpret_cast<short*>(&h);
}

__device__ __forceinline__ bf16x8 cvt8(const float* p) {
    bf16x8 r;
    #pragma unroll
    for (int j = 0; j < 8; j++) r[j] = f2bs(p[j]);
    return r;
}

// ---------- prep: Wt[n][c] = bf16(W_{q|k|v}[c][n&127]), n in [0,384) ----------
__global__ void prep_w_kernel(const float* __restrict__ Wq,
                              const float* __restrict__ Wk,
                              const float* __restrict__ Wv,
                              bf16* __restrict__ Wt) {
    int idx = blockIdx.x * 256 + threadIdx.x;
    if (idx >= NW * CDIM) return;
    int n = idx >> 10, c = idx & (CDIM - 1);
    const float* W = (n < 128) ? Wq : (n < 256) ? Wk : Wv;
    Wt[idx] = __float2bfloat16(W[c * HD + (n & 127)]);
}

// ---------- QKV projection: (16384 x 1024) @ (1024 x 384), bf16 MFMA ----------
// grid 256 (64 rows each), block 256 = 4 waves; wave w owns n-range [96w, 96w+96)
__global__ __launch_bounds__(256) void qkv_proj_kernel(
        const float* __restrict__ x, const bf16* __restrict__ Wt,
        bf16* __restrict__ Q, bf16* __restrict__ K, bf16* __restrict__ Vt) {
    const int tid  = threadIdx.x;
    const int wave = tid >> 6, lane = tid & 63;
    const int quad = lane >> 4, ln = lane & 15;
    const long mbase = (long)blockIdx.x * 64;

    const f32x4 zero = {0.f, 0.f, 0.f, 0.f};
    f32x4 acc[4][6];
    #pragma unroll
    for (int mt = 0; mt < 4; mt++)
        #pragma unroll
        for (int nt = 0; nt < 6; nt++) acc[mt][nt] = zero;

    const float* arow[4];
    const bf16*  brow[6];
    #pragma unroll
    for (int mt = 0; mt < 4; mt++)
        arow[mt] = x + (mbase + mt*16 + ln) * CDIM + quad*8;      // A[m][k]: m=ln, k=quad*8+j
    #pragma unroll
    for (int nt = 0; nt < 6; nt++)
        brow[nt] = Wt + (long)(wave*96 + nt*16 + ln) * CDIM + quad*8; // B[k][n]: n=ln (Wt n-major)

    for (int k0 = 0; k0 < CDIM; k0 += 32) {
        bf16x8 af[4], bfv[6];
        #pragma unroll
        for (int mt = 0; mt < 4; mt++) af[mt]  = cvt8(arow[mt] + k0);  // fp32 -> bf16 inline
        #pragma unroll
        for (int nt = 0; nt < 6; nt++) bfv[nt] = *(const bf16x8*)(brow[nt] + k0);
        #pragma unroll
        for (int mt = 0; mt < 4; mt++)
            #pragma unroll
            for (int nt = 0; nt < 6; nt++)
                acc[mt][nt] = __builtin_amdgcn_mfma_f32_16x16x32_bf16(
                                  af[mt], bfv[nt], acc[mt][nt], 0, 0, 0);
    }

    // C/D layout: col = lane&15, row = quad*4 + r  (verified m89/m91)
    #pragma unroll
    for (int mt = 0; mt < 4; mt++) {
        #pragma unroll
        for (int nt = 0; nt < 6; nt++) {
            const int n = wave*96 + nt*16 + ln;
            #pragma unroll
            for (int r = 0; r < 4; r++) {
                long g = mbase + mt*16 + quad*4 + r;        // global token
                int b = (int)(g >> 11), t = (int)(g & (TT - 1));
                bf16 hv = __float2bfloat16(acc[mt][nt][r]);
                if (n < 128)      Q [((long)b*TT + t)*HD + n]         = hv;
                else if (n < 256) K [((long)b*TT + t)*HD + (n - 128)] = hv;
                else              Vt[((long)b*HD + (n - 256))*TT + t] = hv; // V transposed [h][t]
            }
        }
    }
}

// ---------- causal flash attention ----------
// grid 256 = 8 batches x 32 q-tiles(64 rows); block 256 = 4 waves x 16 q-rows
__global__ __launch_bounds__(256) void attn_kernel(
        const bf16* __restrict__ Q, const bf16* __restrict__ K,
        const bf16* __restrict__ Vt, float* __restrict__ out) {
    // P transpose buffer: per-wave 16x32 bf16, row stride 40 (16B-aligned rows,
    // 2-way-max bank aliasing on the b128 reads -> free)
    __shared__ __align__(16) short pbuf[4][16 * 40];

    const int tid  = threadIdx.x;
    const int wave = tid >> 6, lane = tid & 63;
    const int quad = lane >> 4, ln = lane & 15;
    const int b  = blockIdx.x >> 5;
    const int qt = blockIdx.x & 31;
    const int qb = qt*64 + wave*16;          // this wave's first q row

    const bf16* Qb = Q  + (long)b * TT * HD;
    const bf16* Kb = K  + (long)b * TT * HD;
    const bf16* Vb = Vt + (long)b * HD * TT;

    // Q A-frags for the whole kernel: A[m=ln][k=h], h = kc*32 + quad*8 + j
    bf16x8 qf[4];
    #pragma unroll
    for (int kc = 0; kc < 4; kc++)
        qf[kc] = *(const bf16x8*)(Qb + (long)(qb + ln)*HD + kc*32 + quad*8);

    const f32x4 zero = {0.f, 0.f, 0.f, 0.f};
    f32x4 o[8];
    #pragma unroll
    for (int ht = 0; ht < 8; ht++) o[ht] = zero;
    float mi[4], li[4];
    #pragma unroll
    for (int r = 0; r < 4; r++) { mi[r] = -1e30f; li[r] = 0.f; }

    // Equalized trip count across waves so __syncthreads is uniform.
    // Extra tiles are fully masked: after tile 0 mi is finite (column 0 always
    // unmasked), so alpha=1, sum(p)=0 -> exact no-op.
    const int ntiles = 2*qt + 2;
    for (int kt = 0; kt < ntiles; kt++) {
        const int j0 = kt * 32;

        // S(16x32) = Q(16x128) @ K^T(128x32)
        f32x4 s[2]; s[0] = zero; s[1] = zero;
        #pragma unroll
        for (int kc = 0; kc < 4; kc++) {
            #pragma unroll
            for (int nt = 0; nt < 2; nt++) {
                bf16x8 kf = *(const bf16x8*)(Kb + (long)(j0 + nt*16 + ln)*HD + kc*32 + quad*8);
                s[nt] = __builtin_amdgcn_mfma_f32_16x16x32_bf16(qf[kc], kf, s[nt], 0, 0, 0);
            }
        }

        __syncthreads();   // WAR: previous iteration's pbuf reads done before overwrite

        // online softmax; element (nt, r): row q = qb+quad*4+r, col j = j0+nt*16+ln
        #pragma unroll
        for (int r = 0; r < 4; r++) {
            const int q = qb + quad*4 + r;
            float v0 = s[0][r] * 0.03125f;          // * C^-0.5 = 1/32
            float v1 = s[1][r] * 0.03125f;
            if (j0 + ln      > q) v0 = -1e30f;      // causal mask
            if (j0 + 16 + ln > q) v1 = -1e30f;
            float mx = fmaxf(v0, v1);
            #pragma unroll
            for (int d = 1; d < 16; d <<= 1) mx = fmaxf(mx, __shfl_xor(mx, d));
            float mn = fmaxf(mi[r], mx);
            float alpha = __expf(mi[r] - mn);
            mi[r] = mn;
            float p0 = __expf(v0 - mn);
            float p1 = __expf(v1 - mn);
            float sum = p0 + p1;
            #pragma unroll
            for (int d = 1; d < 16; d <<= 1) sum += __shfl_xor(sum, d);
            li[r] = li[r] * alpha + sum;
            #pragma unroll
            for (int ht = 0; ht < 8; ht++) o[ht][r] *= alpha;
            // C-layout -> LDS (row-major 16x32, stride 40)
            pbuf[wave][(quad*4 + r)*40 + ln     ] = f2bs(p0);
            pbuf[wave][(quad*4 + r)*40 + 16 + ln] = f2bs(p1);
        }

        __syncthreads();   // P visible for the A-layout read

        // P A-frag: A[m=ln][k=quad*8+j]
        bf16x8 pf = *(const bf16x8*)&pbuf[wave][ln*40 + quad*8];
        // O(16x128) += P(16x32) @ V(32x128); V B-frag from Vt: contiguous 16B
        #pragma unroll
        for (int ht = 0; ht < 8; ht++) {
            bf16x8 vf = *(const bf16x8*)(Vb + (long)(ht*16 + ln)*TT + j0 + quad*8);
            o[ht] = __builtin_amdgcn_mfma_f32_16x16x32_bf16(pf, vf, o[ht], 0, 0, 0);
        }
    }

    // fp32 output, coalesced across ln
    #pragma unroll
    for (int ht = 0; ht < 8; ht++) {
        #pragma unroll
        for (int r = 0; r < 4; r++) {
            const int q = qb + quad*4 + r;
            out[((long)b*TT + q)*HD + ht*16 + ln] = o[ht][r] / li[r];
        }
    }
}

extern "C" void kernel_launch(void* const* d_in, const int* in_sizes, int n_in,
                              void* d_out, int out_size, void* d_ws, size_t ws_size,
                              hipStream_t stream) {
    const float* x  = (const float*)d_in[0];
    const float* Wq = (const float*)d_in[1];
    const float* Wk = (const float*)d_in[2];
    const float* Wv = (const float*)d_in[3];
    float* outp = (float*)d_out;   // FP32 output

    // ws: Wt(384x1024) | Q(16384x128) | K(16384x128) | Vt(8x128x2048)  = ~12.75 MB bf16
    bf16* Wt = (bf16*)d_ws;
    bf16* Qm = Wt + (long)NW * CDIM;
    bf16* Km = Qm + (long)NTOK * HD;
    bf16* Vm = Km + (long)NTOK * HD;

    prep_w_kernel<<<(NW * CDIM + 255) / 256, 256, 0, stream>>>(Wq, Wk, Wv, Wt);
    qkv_proj_kernel<<<NTOK / 64, 256, 0, stream>>>(x, Wt, Qm, Km, Vm);
    attn_kernel<<<NB * (TT / 64), 256, 0, stream>>>(Qm, Km, Vm, outp);
}